// Round 4
// baseline (92.279 us; speedup 1.0000x reference)
//
#include <hip/hip_runtime.h>
#include <math.h>

constexpr int B = 2, C = 16, H = 128, W = 128;
constexpr int HW = H * W;
constexpr int KK = 19;

// xpad: [B,16,146,148]; orig (h,w) -> (h+9, w+9); zero pads elsewhere
constexpr int XR = 146, XS = 148, XCH = XR * XS;
constexpr size_t XPAD_ELEMS = (size_t)B * C * XCH;          // 691,456

// ypad: [B,16,130,136]; orig (h,w) -> (h+1, w+4); zero pads elsewhere
constexpr int YR = 130, YS = 136, YCH = YR * YS;
constexpr size_t YPAD_ELEMS = (size_t)B * C * YCH;          // 565,760

__device__ __forceinline__ float4 ld4(const float* p) { return *(const float4*)p; }

// ---------------------------------------------------------------------------
// Kernel 1: 3x3 conv (pad 1) + exact GELU -> xpad.
// Thread = 4 px x 1 oc x 1 ic-half (8 ic). Block = 8 wq x 16 oc x 2 ich = 256.
// Grid = b(2) x h(128) x wquarter(4) = 1024 blocks. Per-ic 9 loads batched.
// ---------------------------------------------------------------------------
__global__ __launch_bounds__(256) void conv1_gelu(
    const float* __restrict__ in, const float* __restrict__ w1,
    const float* __restrict__ b1, float* __restrict__ xpad)
{
    __shared__ float ws[2304];
    __shared__ float bs[16];
    __shared__ float4 red[16][8];
    for (int i = threadIdx.x; i < 2304; i += 256) ws[i] = w1[i];
    if (threadIdx.x < 16) bs[threadIdx.x] = b1[threadIdx.x];
    __syncthreads();

    int wq  = threadIdx.x & 7;
    int oc  = (threadIdx.x >> 3) & 15;
    int ich = threadIdx.x >> 7;
    int blk = blockIdx.x;
    int wt  = blk & 3;
    int h   = (blk >> 2) & 127;
    int b   = blk >> 9;
    int w0  = wt * 32 + wq * 4;

    float4 acc = make_float4(0.f, 0.f, 0.f, 0.f);
    const float4 z4 = make_float4(0.f, 0.f, 0.f, 0.f);
    const float* inb = in + (size_t)b * C * HW;
    int ic0 = ich * 8;

    #pragma unroll
    for (int ic = 0; ic < 8; ++ic) {
        const float* ip = inb + (size_t)(ic0 + ic) * HW;
        float4 Lq[3], Mq[3], Rq[3];
        #pragma unroll
        for (int dy = 0; dy < 3; ++dy) {
            int r = h + dy - 1;
            bool ok = (unsigned)r < (unsigned)H;
            const float* rp = ip + r * W;
            Lq[dy] = (ok && w0 >= 4)   ? ld4(rp + w0 - 4) : z4;
            Mq[dy] = ok                ? ld4(rp + w0)     : z4;
            Rq[dy] = (ok && w0 <= 120) ? ld4(rp + w0 + 4) : z4;
        }
        const float* wp = ws + oc * 144 + (ic0 + ic) * 9;
        #pragma unroll
        for (int dy = 0; dy < 3; ++dy) {
            float a = wp[dy * 3 + 0], g = wp[dy * 3 + 1], c = wp[dy * 3 + 2];
            acc.x = fmaf(a, Lq[dy].w, fmaf(g, Mq[dy].x, fmaf(c, Mq[dy].y, acc.x)));
            acc.y = fmaf(a, Mq[dy].x, fmaf(g, Mq[dy].y, fmaf(c, Mq[dy].z, acc.y)));
            acc.z = fmaf(a, Mq[dy].y, fmaf(g, Mq[dy].z, fmaf(c, Mq[dy].w, acc.z)));
            acc.w = fmaf(a, Mq[dy].z, fmaf(g, Mq[dy].w, fmaf(c, Rq[dy].x, acc.w)));
        }
    }

    if (ich == 1) red[oc][wq] = acc;
    __syncthreads();
    if (ich == 0) {
        float4 o = red[oc][wq];
        float bb = bs[oc];
        acc.x += o.x + bb; acc.y += o.y + bb;
        acc.z += o.z + bb; acc.w += o.w + bb;
        float* xp = xpad + ((size_t)(b * C + oc) * XR + (h + 9)) * XS + (w0 + 9);
        xp[0] = 0.5f * acc.x * (1.0f + erff(acc.x * 0.70710678f));
        xp[1] = 0.5f * acc.y * (1.0f + erff(acc.y * 0.70710678f));
        xp[2] = 0.5f * acc.z * (1.0f + erff(acc.z * 0.70710678f));
        xp[3] = 0.5f * acc.w * (1.0f + erff(acc.w * 0.70710678f));
    }
}

// ---------------------------------------------------------------------------
// Kernel 2: per-pixel 19x19 conv. NO barriers in hot loop, no LDS staging.
// Thread = 4 px x 2 ch (cg, cg+8) x 1 kh-quarter. Block = 8q x 8cg x 4kq = 256
// covering 32 px x 16 ch. Grid = b(2) x h(128) x wb(4) = 1024 (4 blocks/CU).
// Per kh-row: 19 kern float4 + 12 x float4 batched into registers (all
// independent, ~31 loads in flight per thread), then 152 FMAs.
// kern reuse across the 8 cg-groups = L1 broadcast. kq partials via LDS.
// ---------------------------------------------------------------------------
__global__ __launch_bounds__(256, 3) void kpn19(
    const float* __restrict__ xpad,  // [B,16,146,148]
    const float* __restrict__ kern,  // [B,361,128,128]
    float* __restrict__ ypad)        // [B,16,130,136]
{
    __shared__ float4 red[3][8][8][2];

    int q  = threadIdx.x & 7;
    int cg = (threadIdx.x >> 3) & 7;
    int kq = threadIdx.x >> 6;       // wave-uniform kh-quarter
    int blk = blockIdx.x;
    int wb = blk & 3;
    int h  = (blk >> 2) & 127;
    int b  = blk >> 9;
    int w0 = wb * 32 + q * 4;

    float4 acc0 = make_float4(0.f, 0.f, 0.f, 0.f);
    float4 acc1 = make_float4(0.f, 0.f, 0.f, 0.f);

    const float* xb = xpad + (size_t)(b * C + cg) * XCH;
    const float* kb = kern + (size_t)b * 361 * HW + (size_t)h * W + w0;

    #pragma unroll
    for (int r = 0; r < 5; ++r) {
        int kh = kq * 5 + r;
        if (kh > 18) break;          // only kq==3, r==4 (wave-uniform)

        const float* xr0 = xb + (size_t)(h + kh) * XS + w0;
        const float* xr1 = xr0 + (size_t)8 * XCH;
        float4 xq0[6], xq1[6], Kq[19];
        #pragma unroll
        for (int j = 0; j < 6; ++j) { xq0[j] = ld4(xr0 + 4 * j); xq1[j] = ld4(xr1 + 4 * j); }
        const float* kp = kb + (size_t)(kh * 19) * HW;
        #pragma unroll
        for (int kw = 0; kw < KK; ++kw) Kq[kw] = ld4(kp + (size_t)kw * HW);

        float xv0[24], xv1[24];
        #pragma unroll
        for (int j = 0; j < 6; ++j) {
            xv0[4*j+0] = xq0[j].x; xv0[4*j+1] = xq0[j].y;
            xv0[4*j+2] = xq0[j].z; xv0[4*j+3] = xq0[j].w;
            xv1[4*j+0] = xq1[j].x; xv1[4*j+1] = xq1[j].y;
            xv1[4*j+2] = xq1[j].z; xv1[4*j+3] = xq1[j].w;
        }
        #pragma unroll
        for (int kw = 0; kw < KK; ++kw) {
            float4 K = Kq[kw];
            acc0.x = fmaf(xv0[kw + 0], K.x, acc0.x);
            acc0.y = fmaf(xv0[kw + 1], K.y, acc0.y);
            acc0.z = fmaf(xv0[kw + 2], K.z, acc0.z);
            acc0.w = fmaf(xv0[kw + 3], K.w, acc0.w);
            acc1.x = fmaf(xv1[kw + 0], K.x, acc1.x);
            acc1.y = fmaf(xv1[kw + 1], K.y, acc1.y);
            acc1.z = fmaf(xv1[kw + 2], K.z, acc1.z);
            acc1.w = fmaf(xv1[kw + 3], K.w, acc1.w);
        }
    }

    if (kq > 0) { red[kq - 1][cg][q][0] = acc0; red[kq - 1][cg][q][1] = acc1; }
    __syncthreads();
    if (kq == 0) {
        #pragma unroll
        for (int j = 0; j < 3; ++j) {
            float4 r0 = red[j][cg][q][0], r1 = red[j][cg][q][1];
            acc0.x += r0.x; acc0.y += r0.y; acc0.z += r0.z; acc0.w += r0.w;
            acc1.x += r1.x; acc1.y += r1.y; acc1.z += r1.z; acc1.w += r1.w;
        }
        float* yp = ypad + ((size_t)(b * C + cg) * YR + (h + 1)) * YS + (w0 + 4);
        *(float4*)yp = acc0;
        *(float4*)(yp + (size_t)8 * YCH) = acc1;
    }
}

// ---------------------------------------------------------------------------
// Kernel 3: 3x3 conv (pad 1) + sigmoid -> out. Same structure as conv1;
// reads padded y (branch-free).
// ---------------------------------------------------------------------------
__global__ __launch_bounds__(256) void conv2_sig(
    const float* __restrict__ ypad, const float* __restrict__ w2,
    const float* __restrict__ b2, float* __restrict__ out)
{
    __shared__ float ws[2304];
    __shared__ float bs[16];
    __shared__ float4 red[16][8];
    for (int i = threadIdx.x; i < 2304; i += 256) ws[i] = w2[i];
    if (threadIdx.x < 16) bs[threadIdx.x] = b2[threadIdx.x];
    __syncthreads();

    int wq  = threadIdx.x & 7;
    int oc  = (threadIdx.x >> 3) & 15;
    int ich = threadIdx.x >> 7;
    int blk = blockIdx.x;
    int wt  = blk & 3;
    int h   = (blk >> 2) & 127;
    int b   = blk >> 9;
    int w0  = wt * 32 + wq * 4;

    float4 acc = make_float4(0.f, 0.f, 0.f, 0.f);
    int ic0 = ich * 8;

    #pragma unroll
    for (int ic = 0; ic < 8; ++ic) {
        const float* yc = ypad + ((size_t)(b * C + ic0 + ic) * YR + h) * YS + w0;
        float4 Aq[3], Bq[3], Cq[3];
        #pragma unroll
        for (int dy = 0; dy < 3; ++dy) {
            const float* rp = yc + dy * YS;
            Aq[dy] = ld4(rp); Bq[dy] = ld4(rp + 4); Cq[dy] = ld4(rp + 8);
        }
        const float* wp = ws + oc * 144 + (ic0 + ic) * 9;
        #pragma unroll
        for (int dy = 0; dy < 3; ++dy) {
            float a = wp[dy * 3 + 0], g = wp[dy * 3 + 1], c = wp[dy * 3 + 2];
            acc.x = fmaf(a, Aq[dy].w, fmaf(g, Bq[dy].x, fmaf(c, Bq[dy].y, acc.x)));
            acc.y = fmaf(a, Bq[dy].x, fmaf(g, Bq[dy].y, fmaf(c, Bq[dy].z, acc.y)));
            acc.z = fmaf(a, Bq[dy].y, fmaf(g, Bq[dy].z, fmaf(c, Bq[dy].w, acc.z)));
            acc.w = fmaf(a, Bq[dy].z, fmaf(g, Bq[dy].w, fmaf(c, Cq[dy].x, acc.w)));
        }
    }

    if (ich == 1) red[oc][wq] = acc;
    __syncthreads();
    if (ich == 0) {
        float4 o = red[oc][wq];
        float bb = bs[oc];
        acc.x += o.x + bb; acc.y += o.y + bb;
        acc.z += o.z + bb; acc.w += o.w + bb;
        float4 rr;
        rr.x = 1.0f / (1.0f + expf(-acc.x));
        rr.y = 1.0f / (1.0f + expf(-acc.y));
        rr.z = 1.0f / (1.0f + expf(-acc.z));
        rr.w = 1.0f / (1.0f + expf(-acc.w));
        *(float4*)(out + ((size_t)(b * C + oc) * H + h) * W + w0) = rr;
    }
}

// ---------------------------------------------------------------------------
extern "C" void kernel_launch(void* const* d_in, const int* in_sizes, int n_in,
                              void* d_out, int out_size, void* d_ws, size_t ws_size,
                              hipStream_t stream)
{
    const float* input  = (const float*)d_in[0];
    const float* kernel = (const float*)d_in[1];
    const float* w1     = (const float*)d_in[2];
    const float* b1     = (const float*)d_in[3];
    const float* w2     = (const float*)d_in[4];
    const float* b2     = (const float*)d_in[5];
    float* out = (float*)d_out;

    float* xpad = (float*)d_ws;
    float* ypad = xpad + XPAD_ELEMS;

    hipMemsetAsync(d_ws, 0, (XPAD_ELEMS + YPAD_ELEMS) * sizeof(float), stream);

    conv1_gelu<<<1024, 256, 0, stream>>>(input, w1, b1, xpad);
    kpn19<<<1024, 256, 0, stream>>>(xpad, kernel, ypad);
    conv2_sig<<<1024, 256, 0, stream>>>(ypad, w2, b2, out);
}

// Round 5
// 76.037 us; speedup vs baseline: 1.2136x; 1.2136x over previous
//
#include <hip/hip_runtime.h>
#include <math.h>

constexpr int B = 2, C = 16, H = 128, W = 128;
constexpr int HW = H * W;
constexpr int KK = 19;

// xpad: [B,16,146,148]; orig (h,w) -> (h+9, w+9); zero pads elsewhere
constexpr int XR = 146, XS = 148, XCH = XR * XS;
constexpr size_t XPAD_ELEMS = (size_t)B * C * XCH;          // 691,456

// ypad: [B,16,130,136]; orig (h,w) -> (h+1, w+4); zero pads elsewhere
constexpr int YR = 130, YS = 136, YCH = YR * YS;
constexpr size_t YPAD_ELEMS = (size_t)B * C * YCH;          // 565,760

__device__ __forceinline__ float4 ld4(const float* p) { return *(const float4*)p; }

// Inline-asm 16B load: compiler cannot collapse/reorder the batch or shrink
// its register footprint -> guaranteed MLP depth.
__device__ __forceinline__ float4 ald4(const float* p) {
    float4 r;
    asm volatile("global_load_dwordx4 %0, %1, off" : "=v"(r) : "v"(p));
    return r;
}

// ---------------------------------------------------------------------------
// Kernel 1: 3x3 conv (pad 1) + exact GELU -> xpad.
// Thread = 1 px x 4 oc: 9 register taps per ic feed 36 FMAs (4x FLOP/load).
// Block = 128 px (full row) x 2 oc-groups. Grid = b2 x h128 x gg2 = 512.
// Lanes = consecutive px -> coalesced 256B/instr; oc wave-uniform -> LDS
// weight reads broadcast.
// ---------------------------------------------------------------------------
__global__ __launch_bounds__(256) void conv1_gelu(
    const float* __restrict__ in, const float* __restrict__ w1,
    const float* __restrict__ b1, float* __restrict__ xpad)
{
    __shared__ float ws[2304];
    __shared__ float bs[16];
    for (int i = threadIdx.x; i < 2304; i += 256) ws[i] = w1[i];
    if (threadIdx.x < 16) bs[threadIdx.x] = b1[threadIdx.x];
    __syncthreads();

    int px = threadIdx.x & 127;
    int og = threadIdx.x >> 7;           // wave-uniform
    int blk = blockIdx.x;                // 512 = gg2 x h128 x b2
    int gg = blk & 1;
    int h  = (blk >> 1) & 127;
    int b  = blk >> 8;
    int oc0 = (gg * 2 + og) * 4;

    float a0 = 0.f, a1 = 0.f, a2 = 0.f, a3 = 0.f;
    const float* inb = in + (size_t)b * C * HW;

    bool hm = (h > 0), hp = (h < 127);
    bool wm = (px > 0), wp = (px < 127);

    for (int ic = 0; ic < 16; ++ic) {
        const float* p0 = inb + (size_t)ic * HW + (size_t)h * W + px;
        // 9 taps, zero-predicated at borders (independent scalar loads)
        float t00 = (hm && wm) ? p0[-W - 1] : 0.f;
        float t01 = hm         ? p0[-W]     : 0.f;
        float t02 = (hm && wp) ? p0[-W + 1] : 0.f;
        float t10 = wm         ? p0[-1]     : 0.f;
        float t11 =              p0[0];
        float t12 = wp         ? p0[1]      : 0.f;
        float t20 = (hp && wm) ? p0[W - 1]  : 0.f;
        float t21 = hp         ? p0[W]      : 0.f;
        float t22 = (hp && wp) ? p0[W + 1]  : 0.f;

        #pragma unroll
        for (int j = 0; j < 4; ++j) {
            const float* wp9 = ws + (oc0 + j) * 144 + ic * 9;
            float s = fmaf(wp9[0], t00, fmaf(wp9[1], t01, fmaf(wp9[2], t02,
                      fmaf(wp9[3], t10, fmaf(wp9[4], t11, fmaf(wp9[5], t12,
                      fmaf(wp9[6], t20, fmaf(wp9[7], t21, wp9[8] * t22))))))));
            if (j == 0) a0 += s; else if (j == 1) a1 += s;
            else if (j == 2) a2 += s; else a3 += s;
        }
    }

    float* xp = xpad + ((size_t)(b * C + oc0) * XR + (h + 9)) * XS + (px + 9);
    float v;
    v = a0 + bs[oc0 + 0]; xp[0]       = 0.5f * v * (1.0f + erff(v * 0.70710678f));
    v = a1 + bs[oc0 + 1]; xp[XCH]     = 0.5f * v * (1.0f + erff(v * 0.70710678f));
    v = a2 + bs[oc0 + 2]; xp[2 * XCH] = 0.5f * v * (1.0f + erff(v * 0.70710678f));
    v = a3 + bs[oc0 + 3]; xp[3 * XCH] = 0.5f * v * (1.0f + erff(v * 0.70710678f));
}

// ---------------------------------------------------------------------------
// Kernel 2: per-pixel 19x19 conv, asm-forced MLP.
// Thread = 4 px x 1 ch x kh-half. Block = 8wq x 16c x 2half (32px x 16ch).
// Grid = b2 x h128 x wb4 = 1024. Per kh-row: 19 asm K-loads (float4) + 6 x
// float4 in flight -> one vmcnt(0) -> 76 FMAs. No barriers in hot loop.
// ---------------------------------------------------------------------------
__global__ __launch_bounds__(256) void kpn19(
    const float* __restrict__ xpad,  // [B,16,146,148]
    const float* __restrict__ kern,  // [B,361,128,128]
    float* __restrict__ ypad)        // [B,16,130,136]
{
    __shared__ float4 red[16][8];

    int wq = threadIdx.x & 7;
    int c  = (threadIdx.x >> 3) & 15;
    int half = threadIdx.x >> 7;     // wave-uniform
    int blk = blockIdx.x;            // 1024 = wb4 x h128 x b2
    int wb = blk & 3;
    int h  = (blk >> 2) & 127;
    int b  = blk >> 9;
    int w0 = wb * 32 + wq * 4;

    float4 acc = make_float4(0.f, 0.f, 0.f, 0.f);

    const float* xb = xpad + (size_t)(b * C + c) * XCH;
    const float* kb = kern + (size_t)b * 361 * HW + (size_t)h * W + w0;

    int kh0 = half * 10;
    int nrow = 10 - half;            // half0: kh 0..9, half1: kh 10..18

    for (int r = 0; r < nrow; ++r) {
        int kh = kh0 + r;
        const float* kp = kb + (size_t)(kh * 19) * HW;
        float4 K[19];
        #pragma unroll
        for (int kw = 0; kw < KK; ++kw)
            K[kw] = ald4(kp + (size_t)kw * HW);

        const float* xr = xb + (size_t)(h + kh) * XS + w0;
        float4 xq[6];
        #pragma unroll
        for (int j = 0; j < 6; ++j) xq[j] = ld4(xr + 4 * j);

        asm volatile("s_waitcnt vmcnt(0)" ::: "memory");
        __builtin_amdgcn_sched_barrier(0);

        float xv[24];
        #pragma unroll
        for (int j = 0; j < 6; ++j) {
            xv[4*j+0] = xq[j].x; xv[4*j+1] = xq[j].y;
            xv[4*j+2] = xq[j].z; xv[4*j+3] = xq[j].w;
        }
        #pragma unroll
        for (int kw = 0; kw < KK; ++kw) {
            acc.x = fmaf(xv[kw + 0], K[kw].x, acc.x);
            acc.y = fmaf(xv[kw + 1], K[kw].y, acc.y);
            acc.z = fmaf(xv[kw + 2], K[kw].z, acc.z);
            acc.w = fmaf(xv[kw + 3], K[kw].w, acc.w);
        }
    }

    if (half == 1) red[c][wq] = acc;
    __syncthreads();
    if (half == 0) {
        float4 o = red[c][wq];
        acc.x += o.x; acc.y += o.y; acc.z += o.z; acc.w += o.w;
        float* yp = ypad + ((size_t)(b * C + c) * YR + (h + 1)) * YS + (w0 + 4);
        *(float4*)yp = acc;
    }
}

// ---------------------------------------------------------------------------
// Kernel 3: 3x3 conv (pad 1) + sigmoid -> out. Same structure as conv1,
// branch-free reads from padded y.
// ---------------------------------------------------------------------------
__global__ __launch_bounds__(256) void conv2_sig(
    const float* __restrict__ ypad, const float* __restrict__ w2,
    const float* __restrict__ b2, float* __restrict__ out)
{
    __shared__ float ws[2304];
    __shared__ float bs[16];
    for (int i = threadIdx.x; i < 2304; i += 256) ws[i] = w2[i];
    if (threadIdx.x < 16) bs[threadIdx.x] = b2[threadIdx.x];
    __syncthreads();

    int px = threadIdx.x & 127;
    int og = threadIdx.x >> 7;
    int blk = blockIdx.x;
    int gg = blk & 1;
    int h  = (blk >> 1) & 127;
    int b  = blk >> 8;
    int oc0 = (gg * 2 + og) * 4;

    float a0 = 0.f, a1 = 0.f, a2 = 0.f, a3 = 0.f;

    for (int ic = 0; ic < 16; ++ic) {
        // padded y: orig (h,w) at (h+1, w+4); need rows h-1..h+1, cols px-1..px+1
        const float* p0 = ypad + ((size_t)(b * C + ic) * YR + (h + 1)) * YS + (px + 4);
        float t00 = p0[-YS - 1], t01 = p0[-YS], t02 = p0[-YS + 1];
        float t10 = p0[-1],      t11 = p0[0],   t12 = p0[1];
        float t20 = p0[YS - 1],  t21 = p0[YS],  t22 = p0[YS + 1];

        #pragma unroll
        for (int j = 0; j < 4; ++j) {
            const float* wp9 = ws + (oc0 + j) * 144 + ic * 9;
            float s = fmaf(wp9[0], t00, fmaf(wp9[1], t01, fmaf(wp9[2], t02,
                      fmaf(wp9[3], t10, fmaf(wp9[4], t11, fmaf(wp9[5], t12,
                      fmaf(wp9[6], t20, fmaf(wp9[7], t21, wp9[8] * t22))))))));
            if (j == 0) a0 += s; else if (j == 1) a1 += s;
            else if (j == 2) a2 += s; else a3 += s;
        }
    }

    float* op = out + ((size_t)(b * C + oc0) * H + h) * W + px;
    float v;
    v = a0 + bs[oc0 + 0]; op[0]      = 1.0f / (1.0f + expf(-v));
    v = a1 + bs[oc0 + 1]; op[HW]     = 1.0f / (1.0f + expf(-v));
    v = a2 + bs[oc0 + 2]; op[2 * HW] = 1.0f / (1.0f + expf(-v));
    v = a3 + bs[oc0 + 3]; op[3 * HW] = 1.0f / (1.0f + expf(-v));
}

// ---------------------------------------------------------------------------
extern "C" void kernel_launch(void* const* d_in, const int* in_sizes, int n_in,
                              void* d_out, int out_size, void* d_ws, size_t ws_size,
                              hipStream_t stream)
{
    const float* input  = (const float*)d_in[0];
    const float* kernel = (const float*)d_in[1];
    const float* w1     = (const float*)d_in[2];
    const float* b1     = (const float*)d_in[3];
    const float* w2     = (const float*)d_in[4];
    const float* b2     = (const float*)d_in[5];
    float* out = (float*)d_out;

    float* xpad = (float*)d_ws;
    float* ypad = xpad + XPAD_ELEMS;

    hipMemsetAsync(d_ws, 0, (XPAD_ELEMS + YPAD_ELEMS) * sizeof(float), stream);

    conv1_gelu<<<512, 256, 0, stream>>>(input, w1, b1, xpad);
    kpn19<<<1024, 256, 0, stream>>>(xpad, kernel, ypad);
    conv2_sig<<<512, 256, 0, stream>>>(ypad, w2, b2, out);
}